// Round 6
// baseline (506.822 us; speedup 1.0000x reference)
//
#include <hip/hip_runtime.h>
#include <hip/hip_cooperative_groups.h>
#include <math.h>

namespace cg = cooperative_groups;

#define BB   32
#define HHI  56
#define WWI  56
#define CC   256
#define LL   3136      // H*W
#define SS   16
#define NCH  56        // chunks per batch
#define CHL  56        // chunk length
#define WPP  16        // positions per wave-unit in reduction phases
#define NU   (BB * LL / WPP)   // 6272 wave-units
#define NSL  98        // fallback path slice count
#define EPSV 1e-5f

__device__ __forceinline__ float softplusf(float z) {
    return fmaxf(z, 0.f) + __logf(1.f + __expf(-fabsf(z)));
}
__device__ __forceinline__ float sigmoidf(float z) {
    return 1.f / (1.f + __expf(-z));
}

struct KParams {
    const float *x, *ca_w1, *ca_w2, *lsa_w, *A, *dw, *db, *Bw, *Bb, *Cw, *Cb, *bng, *bnb;
    float *out;
    float4 *mdd;
    float *gate, *m, *cmax, *sy, *ssg, *scv, *shv, *Pp, *Qq, *hst, *psum, *pmax, *pb;
};

// ==================== cooperative mega-kernel ====================
__global__ __launch_bounds__(512, 4) void k_mega(KParams p) {
    cg::grid_group gridg = cg::this_grid();
    const int tid  = threadIdx.x;
    const int lane = tid & 63;
    const int wv   = tid >> 6;
    const int gw   = blockIdx.x * 8 + wv;     // global wave id
    const int NW   = gridDim.x * 8;           // total waves
    const float4* x4 = (const float4*)p.x;

    __shared__ float s_avg[2][CC], s_mxs[2][CC], s_h[2][16];
    __shared__ float s_bn[16][2];

    // ---- P1: CA spatial partials (wave-unit = 16 positions) ----
    for (int u = gw; u < NU; u += NW) {
        int b  = u / (LL / WPP);
        int sl = u - b * (LL / WPP);
        size_t base = ((size_t)b * LL + sl * WPP) * 64 + lane;
        float4 s  = make_float4(0.f, 0.f, 0.f, 0.f);
        float4 mx = make_float4(-1e30f, -1e30f, -1e30f, -1e30f);
#pragma unroll
        for (int k = 0; k < WPP; k++) {
            float4 v = x4[base + (size_t)k * 64];
            s.x += v.x; s.y += v.y; s.z += v.z; s.w += v.w;
            mx.x = fmaxf(mx.x, v.x); mx.y = fmaxf(mx.y, v.y);
            mx.z = fmaxf(mx.z, v.z); mx.w = fmaxf(mx.w, v.w);
        }
        ((float4*)p.psum)[(size_t)u * 64 + lane] = s;
        ((float4*)p.pmax)[(size_t)u * 64 + lane] = mx;
    }
    gridg.sync();

    // ---- P2: CA FC -> gate (blocks 0..15, 2 batches per block) ----
    if (blockIdx.x < 16) {
        const int half = tid >> 8;       // 0..1
        const int c    = tid & 255;
        const int b    = blockIdx.x * 2 + half;
        float s = 0.f, mx = -1e30f;
        for (int k = 0; k < 196; k++) {
            s  += p.psum[(b * 196 + k) * 256 + c];
            mx = fmaxf(mx, p.pmax[(b * 196 + k) * 256 + c]);
        }
        s_avg[half][c] = s * (1.f / 3136.f);
        s_mxs[half][c] = mx;
        __syncthreads();
        const int r = c >> 4, l = c & 15;
        float pa = 0.f, pm = 0.f;
        for (int j = 0; j < 16; j++) {
            float w = p.ca_w1[r * 256 + l * 16 + j];
            pa += s_avg[half][l * 16 + j] * w;
            pm += s_mxs[half][l * 16 + j] * w;
        }
#pragma unroll
        for (int d = 1; d < 16; d <<= 1) { pa += __shfl_xor(pa, d); pm += __shfl_xor(pm, d); }
        if (l == 0) s_h[half][r] = fmaxf(pa, 0.f) + fmaxf(pm, 0.f);
        __syncthreads();
        float o = 0.f;
#pragma unroll
        for (int r2 = 0; r2 < 16; r2++) o += s_h[half][r2] * p.ca_w2[c * 16 + r2];
        p.gate[b * 256 + c] = sigmoidf(o);
    }
    gridg.sync();

    // ---- P3: per-position channel mean/max + delta precompute ----
    {
        const float dwv = p.dw[0], dbv = p.db[0];
        for (int u = gw; u < BB * LL / 4; u += NW) {
            int p0 = u * 4;
            int b = p0 / LL;
            float4 g = ((const float4*)p.gate)[b * 64 + lane];
#pragma unroll
            for (int k = 0; k < 4; k++) {
                int pos = p0 + k;
                float4 v = x4[(size_t)pos * 64 + lane];
                v.x *= g.x; v.y *= g.y; v.z *= g.z; v.w *= g.w;
                float s  = v.x + v.y + v.z + v.w;
                float mm = fmaxf(fmaxf(v.x, v.y), fmaxf(v.z, v.w));
#pragma unroll
                for (int d = 1; d < 64; d <<= 1) {
                    s += __shfl_xor(s, d);
                    mm = fmaxf(mm, __shfl_xor(mm, d));
                }
                if (lane == 0) {
                    float mv = s * (1.f / 256.f);
                    p.m[pos] = mv;
                    p.cmax[pos] = mm;
                    float dl = softplusf(mv * dwv + dbv);
                    p.mdd[pos] = make_float4(mv, dl, dl * mv, 0.f);
                }
            }
        }
    }
    gridg.sync();

    // ---- P4: scan phase A — per-chunk (P, Q) ----
    {
        const int sub = lane >> 4, s = lane & 15;
        const float As = p.A[s], Bws = p.Bw[s], Bbs = p.Bb[s];
        for (int q = gw; q < 448; q += NW) {
            int gidx = q * 4 + sub;
            int b = gidx / NCH, ch = gidx - b * NCH;
            int base = b * LL + ch * CHL;
            float sumd = 0.f, Q = 0.f;
            for (int t = 0; t < CHL; t++) {
                float4 md = p.mdd[base + t];        // {m, delta, dm, .}
                float a = __expf(md.y * As);
                Q = a * Q + md.z * (md.x * Bws + Bbs);
                sumd += md.y;
            }
            int idx = ch * 512 + b * 16 + s;
            p.Pp[idx] = __expf(sumd * As);
            p.Qq[idx] = Q;
        }
    }
    gridg.sync();

    // ---- P5: scan phase B — serial chunk-prefix combine (8 waves) ----
    if (gw < 8) {
        const int bsub = lane >> 4, s = lane & 15;
        const int b = gw * 4 + bsub;
        float h = 0.f;
        for (int ch = 0; ch < NCH; ch++) {
            int idx = ch * 512 + b * 16 + s;
            p.hst[idx] = h;
            h = p.Pp[idx] * h + p.Qq[idx];
        }
    }
    gridg.sync();

    // ---- P6: scan phase C (waves 0..447)  ||  LSA conv (waves 448+) ----
    {
        const int sub = lane >> 4, s = lane & 15;
        if (gw < 448) {
            const float As = p.A[s], Bws = p.Bw[s], Bbs = p.Bb[s];
            const float Cws = p.Cw[s], Cbs = p.Cb[s];
            for (int q = gw; q < 448; q += NW) {
                int gidx = q * 4 + sub;
                int b = gidx / NCH, ch = gidx - b * NCH;
                int base = b * LL + ch * CHL;
                float h = p.hst[ch * 512 + b * 16 + s];
                for (int t = 0; t < CHL; t++) {
                    float4 md = p.mdd[base + t];
                    float a = __expf(md.y * As);
                    h = a * h + md.z * (md.x * Bws + Bbs);
                    float pr = h * (md.x * Cws + Cbs);
#pragma unroll
                    for (int d = 1; d < 16; d <<= 1) pr += __shfl_xor(pr, d);
                    if (s == 0) p.sy[base + t] = sigmoidf(pr);
                }
            }
        } else {
            for (int w2 = gw - 448; w2 < 1568; w2 += NW - 448) {
                int pos = w2 * 64 + lane;               // < 100352 exactly
                int b = pos / LL;
                int ii = pos - b * LL;
                int h0 = ii / WWI, w0 = ii - h0 * WWI;
                const float* mb = p.m + b * LL;
                const float* cb = p.cmax + b * LL;
                float acc = 0.f;
#pragma unroll
                for (int kh = 0; kh < 7; kh++) {
                    int hh = h0 + kh - 3;
                    if ((unsigned)hh >= (unsigned)HHI) continue;
                    int rb = hh * WWI;
#pragma unroll
                    for (int kw = 0; kw < 7; kw++) {
                        int ww = w0 + kw - 3;
                        if ((unsigned)ww >= (unsigned)WWI) continue;
                        acc += mb[rb + ww] * p.lsa_w[(kh * 7 + kw) * 2]
                             + cb[rb + ww] * p.lsa_w[(kh * 7 + kw) * 2 + 1];
                    }
                }
                p.ssg[pos] = sigmoidf(acc);
            }
        }
    }
    gridg.sync();

    // ---- P7: BN partial stats (wave-unit = 16 positions) ----
    for (int u = gw; u < NU; u += NW) {
        int b  = u / (LL / WPP);
        int sl = u - b * (LL / WPP);
        int pos0 = b * LL + sl * WPP;
        float4 g = ((const float4*)p.gate)[b * 64 + lane];
        float4 s = make_float4(0.f, 0.f, 0.f, 0.f);
        float4 q = make_float4(0.f, 0.f, 0.f, 0.f);
#pragma unroll
        for (int k = 0; k < WPP; k++) {
            int pos = pos0 + k;
            float4 v = x4[(size_t)pos * 64 + lane];
            float g2 = p.sy[pos] + p.ssg[pos];
            float fx = v.x * g.x * g2, fy = v.y * g.y * g2;
            float fz = v.z * g.z * g2, fw = v.w * g.w * g2;
            s.x += fx; s.y += fy; s.z += fz; s.w += fw;
            q.x += fx * fx; q.y += fy * fy; q.z += fz * fz; q.w += fw * fw;
        }
        ((float4*)p.pb)[(size_t)u * 128 + lane]      = s;
        ((float4*)p.pb)[(size_t)u * 128 + 64 + lane] = q;
    }
    gridg.sync();

    // ---- P8: BN reduce + finalize (blocks 0..15, 16 channels each) ----
    if (blockIdx.x < 16) {
        const int rep   = tid & 15;
        const int kind  = (tid >> 4) & 1;
        const int c_loc = tid >> 5;                 // 0..15
        const int col   = kind * 256 + blockIdx.x * 16 + c_loc;
        float acc = 0.f;
        for (int k = 0; k < 392; k++) {
            acc += p.pb[(size_t)(rep + k * 16) * 512 + col];
        }
#pragma unroll
        for (int d = 1; d < 16; d <<= 1) acc += __shfl_xor(acc, d);
        if (rep == 0) s_bn[c_loc][kind] = acc;
        __syncthreads();
        if (tid < 16) {
            const int c = blockIdx.x * 16 + tid;
            const float inv = 1.f / (float)(BB * LL);
            float mean = s_bn[tid][0] * inv;
            float var  = s_bn[tid][1] * inv - mean * mean;
            float sv = p.bng[c] * rsqrtf(var + EPSV);
            p.scv[c] = sv;
            p.shv[c] = p.bnb[c] - mean * sv;
        }
    }
    gridg.sync();

    // ---- P9: normalize + ReLU + write ----
    {
        float4 scv4 = ((const float4*)p.scv)[lane];
        float4 shv4 = ((const float4*)p.shv)[lane];
        for (int u = gw; u < BB * LL / 4; u += NW) {
            int p0 = u * 4;
            int b = p0 / LL;
            float4 g = ((const float4*)p.gate)[b * 64 + lane];
#pragma unroll
            for (int k = 0; k < 4; k++) {
                int pos = p0 + k;
                float4 v = x4[(size_t)pos * 64 + lane];
                float g2 = p.sy[pos] + p.ssg[pos];
                float4 o;
                o.x = fmaxf(v.x * g.x * g2 * scv4.x + shv4.x, 0.f);
                o.y = fmaxf(v.y * g.y * g2 * scv4.y + shv4.y, 0.f);
                o.z = fmaxf(v.z * g.z * g2 * scv4.z + shv4.z, 0.f);
                o.w = fmaxf(v.w * g.w * g2 * scv4.w + shv4.w, 0.f);
                ((float4*)p.out)[(size_t)pos * 64 + lane] = o;
            }
        }
    }
}

// ==================== fallback split kernels (R5 path) ====================
__global__ void k_ca_partial(const float* __restrict__ x,
                             float* __restrict__ psum, float* __restrict__ pmax) {
    const int b = blockIdx.x, sl = blockIdx.y;
    const int wv = threadIdx.x >> 6, l = threadIdx.x & 63;
    const float4* x4 = (const float4*)x;
    const size_t base = ((size_t)b * LL + sl * 32) * 64;
    float4 s  = make_float4(0.f, 0.f, 0.f, 0.f);
    float4 mx = make_float4(-1e30f, -1e30f, -1e30f, -1e30f);
#pragma unroll
    for (int k = 0; k < 8; k++) {
        float4 v = x4[base + (size_t)(k * 4 + wv) * 64 + l];
        s.x += v.x; s.y += v.y; s.z += v.z; s.w += v.w;
        mx.x = fmaxf(mx.x, v.x); mx.y = fmaxf(mx.y, v.y);
        mx.z = fmaxf(mx.z, v.z); mx.w = fmaxf(mx.w, v.w);
    }
    __shared__ float4 ls[4][64], lm[4][64];
    ls[wv][l] = s; lm[wv][l] = mx;
    __syncthreads();
    if (wv == 0) {
#pragma unroll
        for (int w = 1; w < 4; w++) {
            float4 a = ls[w][l], m2 = lm[w][l];
            s.x += a.x; s.y += a.y; s.z += a.z; s.w += a.w;
            mx.x = fmaxf(mx.x, m2.x); mx.y = fmaxf(mx.y, m2.y);
            mx.z = fmaxf(mx.z, m2.z); mx.w = fmaxf(mx.w, m2.w);
        }
        ((float4*)psum)[(b * NSL + sl) * 64 + l] = s;
        ((float4*)pmax)[(b * NSL + sl) * 64 + l] = mx;
    }
}

__global__ void k_ca_fc(const float* __restrict__ psum, const float* __restrict__ pmax,
                        const float* __restrict__ w1, const float* __restrict__ w2,
                        float* __restrict__ gate) {
    const int b = blockIdx.x, tid = threadIdx.x;
    __shared__ float avg[CC], mxs[CC], hsum[16];
    float s = 0.f, mx = -1e30f;
    for (int k = 0; k < NSL; k++) {
        s += psum[(b * NSL + k) * CC + tid];
        mx = fmaxf(mx, pmax[(b * NSL + k) * CC + tid]);
    }
    avg[tid] = s * (1.f / 3136.f);
    mxs[tid] = mx;
    __syncthreads();
    const int r = tid >> 4, l = tid & 15;
    float pa = 0.f, pm = 0.f;
    for (int j = 0; j < 16; j++) {
        float w = w1[r * CC + l * 16 + j];
        pa += avg[l * 16 + j] * w;
        pm += mxs[l * 16 + j] * w;
    }
#pragma unroll
    for (int d = 1; d < 16; d <<= 1) { pa += __shfl_xor(pa, d); pm += __shfl_xor(pm, d); }
    if (l == 0) hsum[r] = fmaxf(pa, 0.f) + fmaxf(pm, 0.f);
    __syncthreads();
    float o = 0.f;
#pragma unroll
    for (int r2 = 0; r2 < 16; r2++) o += hsum[r2] * w2[tid * 16 + r2];
    gate[b * CC + tid] = sigmoidf(o);
}

__global__ void k_pos_reduce(const float* __restrict__ x, const float* __restrict__ gate,
                             const float* __restrict__ dw, const float* __restrict__ db,
                             float* __restrict__ m, float* __restrict__ cmax,
                             float4* __restrict__ mdd) {
    const int wv = threadIdx.x >> 6, l = threadIdx.x & 63;
    const int b = blockIdx.y;
    float4 g = ((const float4*)gate)[b * 64 + l];
    const float dwv = dw[0], dbv = db[0];
#pragma unroll
    for (int k = 0; k < 4; k++) {
        const int pos = b * LL + blockIdx.x * 16 + k * 4 + wv;
        float4 v = ((const float4*)x)[(size_t)pos * 64 + l];
        v.x *= g.x; v.y *= g.y; v.z *= g.z; v.w *= g.w;
        float s  = v.x + v.y + v.z + v.w;
        float mm = fmaxf(fmaxf(v.x, v.y), fmaxf(v.z, v.w));
#pragma unroll
        for (int d = 1; d < 64; d <<= 1) {
            s += __shfl_xor(s, d);
            mm = fmaxf(mm, __shfl_xor(mm, d));
        }
        if (l == 0) {
            float mv = s * (1.f / 256.f);
            m[pos] = mv;
            cmax[pos] = mm;
            float dl = softplusf(mv * dwv + dbv);
            mdd[pos] = make_float4(mv, dl, dl * mv, 0.f);
        }
    }
}

__global__ void k_gsa2(const float4* __restrict__ mdd,
                       const float* __restrict__ m, const float* __restrict__ cmax,
                       const float* __restrict__ Bw, const float* __restrict__ Bb,
                       const float* __restrict__ Cw, const float* __restrict__ Cb,
                       const float* __restrict__ A,  const float* __restrict__ wc,
                       float* __restrict__ sy, float* __restrict__ ssg) {
    __shared__ __align__(16) char smem[60928];
    const int tid = threadIdx.x;
    if (blockIdx.x < BB) {
        const int b = blockIdx.x;
        float4* mddl = (float4*)smem;
        float*  Pl   = (float*)(smem + 50176);
        float*  Ql   = (float*)(smem + 50176 + 3584);
        float*  hl   = (float*)(smem + 50176 + 7168);
        for (int i = tid; i < LL; i += 896) mddl[i] = mdd[b * LL + i];
        __syncthreads();
        const int g = tid >> 4, s = tid & 15;
        const float As = A[s], Bws = Bw[s], Bbs = Bb[s];
        const float Cws = Cw[s], Cbs = Cb[s];
        float sumd = 0.f, Q = 0.f;
        for (int t = 0; t < CHL; t++) {
            float4 md = mddl[g * CHL + t];
            float a = __expf(md.y * As);
            Q = a * Q + md.z * (md.x * Bws + Bbs);
            sumd += md.y;
        }
        Pl[g * 16 + s] = __expf(sumd * As);
        Ql[g * 16 + s] = Q;
        __syncthreads();
        if (g == 0) {
            float h = 0.f;
            for (int ch = 0; ch < NCH; ch++) {
                hl[ch * 16 + s] = h;
                h = Pl[ch * 16 + s] * h + Ql[ch * 16 + s];
            }
        }
        __syncthreads();
        float h = hl[g * 16 + s];
        for (int t = 0; t < CHL; t++) {
            float4 md = mddl[g * CHL + t];
            float a = __expf(md.y * As);
            h = a * h + md.z * (md.x * Bws + Bbs);
            float p = h * (md.x * Cws + Cbs);
#pragma unroll
            for (int d = 1; d < 16; d <<= 1) p += __shfl_xor(p, d);
            if (s == 0) sy[b * LL + g * CHL + t] = sigmoidf(p);
        }
    } else {
        const int b = blockIdx.x - BB;
        float* ml = (float*)smem;
        float* cl = (float*)(smem + 12544);
        float* wl = (float*)(smem + 25088);
        for (int i = tid; i < LL; i += 896) {
            ml[i] = m[b * LL + i];
            cl[i] = cmax[b * LL + i];
        }
        if (tid < 98) wl[tid] = wc[tid];
        __syncthreads();
        for (int pos = tid; pos < LL; pos += 896) {
            const int h0 = pos / WWI, w0 = pos - h0 * WWI;
            float acc = 0.f;
#pragma unroll
            for (int kh = 0; kh < 7; kh++) {
                int hh = h0 + kh - 3;
                if ((unsigned)hh >= (unsigned)HHI) continue;
                const int rb = hh * WWI;
#pragma unroll
                for (int kw = 0; kw < 7; kw++) {
                    int ww = w0 + kw - 3;
                    if ((unsigned)ww >= (unsigned)WWI) continue;
                    acc += ml[rb + ww] * wl[(kh * 7 + kw) * 2]
                         + cl[rb + ww] * wl[(kh * 7 + kw) * 2 + 1];
                }
            }
            ssg[b * LL + pos] = sigmoidf(acc);
        }
    }
}

__global__ void k_bnstat(const float* __restrict__ x, const float* __restrict__ gate,
                         const float* __restrict__ sy, const float* __restrict__ ssg,
                         float* __restrict__ pb) {
    const int b = blockIdx.x, sl = blockIdx.y;
    const int wv = threadIdx.x >> 6, l = threadIdx.x & 63;
    const float4* x4 = (const float4*)x;
    float4 g = ((const float4*)gate)[b * 64 + l];
    float4 s = make_float4(0.f, 0.f, 0.f, 0.f);
    float4 q = make_float4(0.f, 0.f, 0.f, 0.f);
#pragma unroll
    for (int k = 0; k < 8; k++) {
        int pos = b * LL + sl * 32 + k * 4 + wv;
        float4 v = x4[(size_t)pos * 64 + l];
        float g2 = sy[pos] + ssg[pos];
        float fx = v.x * g.x * g2, fy = v.y * g.y * g2, fz = v.z * g.z * g2, fw = v.w * g.w * g2;
        s.x += fx; s.y += fy; s.z += fz; s.w += fw;
        q.x += fx * fx; q.y += fy * fy; q.z += fz * fz; q.w += fw * fw;
    }
    __shared__ float4 ls[4][64], lq[4][64];
    ls[wv][l] = s; lq[wv][l] = q;
    __syncthreads();
    if (wv == 0) {
#pragma unroll
        for (int w = 1; w < 4; w++) {
            float4 a = ls[w][l], c = lq[w][l];
            s.x += a.x; s.y += a.y; s.z += a.z; s.w += a.w;
            q.x += c.x; q.y += c.y; q.z += c.z; q.w += c.w;
        }
        ((float4*)pb)[(b * NSL + sl) * 128 + l] = s;
        ((float4*)pb)[(b * NSL + sl) * 128 + 64 + l] = q;
    }
}

__global__ void k_bnfin(const float* __restrict__ pb,
                        const float* __restrict__ gamma, const float* __restrict__ beta,
                        float* __restrict__ sc, float* __restrict__ sh) {
    const int c = blockIdx.x;
    const int tid = threadIdx.x;
    float s0 = 0.f, q0 = 0.f;
    for (int sl = tid; sl < BB * NSL; sl += 256) {
        s0 += pb[(size_t)sl * 512 + c];
        q0 += pb[(size_t)sl * 512 + 256 + c];
    }
    __shared__ float rs[256], rq[256];
    rs[tid] = s0; rq[tid] = q0;
    __syncthreads();
    for (int d = 128; d > 0; d >>= 1) {
        if (tid < d) { rs[tid] += rs[tid + d]; rq[tid] += rq[tid + d]; }
        __syncthreads();
    }
    if (tid == 0) {
        const float inv = 1.f / (float)(BB * LL);
        float mean = rs[0] * inv;
        float var  = rq[0] * inv - mean * mean;
        float sv = gamma[c] * rsqrtf(var + EPSV);
        sc[c] = sv;
        sh[c] = beta[c] - mean * sv;
    }
}

__global__ void k_final(const float* __restrict__ x, const float* __restrict__ gate,
                        const float* __restrict__ sy, const float* __restrict__ ssg,
                        const float* __restrict__ sc, const float* __restrict__ sh,
                        float* __restrict__ out) {
    const int wv = threadIdx.x >> 6, l = threadIdx.x & 63;
    const int b = blockIdx.y;
    const float4 scv = ((const float4*)sc)[l];
    const float4 shv = ((const float4*)sh)[l];
    const float4 g = ((const float4*)gate)[b * 64 + l];
#pragma unroll
    for (int k = 0; k < 4; k++) {
        const int pos = b * LL + blockIdx.x * 16 + k * 4 + wv;
        float4 v = ((const float4*)x)[(size_t)pos * 64 + l];
        float g2 = sy[pos] + ssg[pos];
        float4 o;
        o.x = fmaxf(v.x * g.x * g2 * scv.x + shv.x, 0.f);
        o.y = fmaxf(v.y * g.y * g2 * scv.y + shv.y, 0.f);
        o.z = fmaxf(v.z * g.z * g2 * scv.z + shv.z, 0.f);
        o.w = fmaxf(v.w * g.w * g2 * scv.w + shv.w, 0.f);
        ((float4*)out)[(size_t)pos * 64 + l] = o;
    }
}

extern "C" void kernel_launch(void* const* d_in, const int* in_sizes, int n_in,
                              void* d_out, int out_size, void* d_ws, size_t ws_size,
                              hipStream_t stream) {
    const float* x     = (const float*)d_in[0];
    const float* ca_w1 = (const float*)d_in[1];
    const float* ca_w2 = (const float*)d_in[2];
    const float* lsa_w = (const float*)d_in[3];
    const float* A     = (const float*)d_in[4];
    const float* d_wp  = (const float*)d_in[5];
    const float* d_bp  = (const float*)d_in[6];
    const float* B_wp  = (const float*)d_in[7];
    const float* B_bp  = (const float*)d_in[8];
    const float* C_wp  = (const float*)d_in[9];
    const float* C_bp  = (const float*)d_in[10];
    const float* bn_g  = (const float*)d_in[11];
    const float* bn_b  = (const float*)d_in[12];
    float* out = (float*)d_out;

    float* ws = (float*)d_ws;
    float4* mdd  = (float4*)ws;                    // 100352 float4
    float* gate  = ws + 401408;                    // 8192
    float* m     = gate + 8192;                    // 100352
    float* cmax  = m + 100352;                     // 100352
    float* sy    = cmax + 100352;                  // 100352
    float* ssg   = sy + 100352;                    // 100352
    float* scv   = ssg + 100352;                   // 256
    float* shv   = scv + 256;                      // 256
    float* Pp    = shv + 256;                      // 28672
    float* Qq    = Pp + 28672;                     // 28672
    float* hst   = Qq + 28672;                     // 28672
    float* psum  = hst + 28672;                    // 1605632 (mega) / 802816 (fallback)
    float* pmax  = psum + 1605632;                 // 1605632
    float* pb    = pmax + 1605632;                 // 3211264
    // total ~7.25M floats = 29 MB

    KParams kp;
    kp.x = x; kp.ca_w1 = ca_w1; kp.ca_w2 = ca_w2; kp.lsa_w = lsa_w; kp.A = A;
    kp.dw = d_wp; kp.db = d_bp; kp.Bw = B_wp; kp.Bb = B_bp; kp.Cw = C_wp; kp.Cb = C_bp;
    kp.bng = bn_g; kp.bnb = bn_b; kp.out = out;
    kp.mdd = mdd; kp.gate = gate; kp.m = m; kp.cmax = cmax; kp.sy = sy; kp.ssg = ssg;
    kp.scv = scv; kp.shv = shv; kp.Pp = Pp; kp.Qq = Qq; kp.hst = hst;
    kp.psum = psum; kp.pmax = pmax; kp.pb = pb;

    int maxb = 0;
    hipError_t e = hipOccupancyMaxActiveBlocksPerMultiprocessor(&maxb, k_mega, 512, 0);
    if (e != hipSuccess || maxb < 1) maxb = 1;
    int grid = maxb * 256;
    if (grid > 1024) grid = 1024;

    void* args[] = { (void*)&kp };
    e = hipLaunchCooperativeKernel((const void*)k_mega, dim3(grid), dim3(512),
                                   args, 0, stream);
    if (e != hipSuccess) {
        // -------- fallback: R5 split-kernel path --------
        (void)hipGetLastError();   // clear error state
        k_ca_partial<<<dim3(BB, NSL), 256, 0, stream>>>(x, psum, pmax);
        k_ca_fc<<<BB, 256, 0, stream>>>(psum, pmax, ca_w1, ca_w2, gate);
        k_pos_reduce<<<dim3(LL / 16, BB), 256, 0, stream>>>(x, gate, d_wp, d_bp, m, cmax, mdd);
        k_gsa2<<<2 * BB, 896, 0, stream>>>(mdd, m, cmax, B_wp, B_bp, C_wp, C_bp, A, lsa_w, sy, ssg);
        k_bnstat<<<dim3(BB, NSL), 256, 0, stream>>>(x, gate, sy, ssg, pb);
        k_bnfin<<<CC, 256, 0, stream>>>(pb, bn_g, bn_b, scv, shv);
        k_final<<<dim3(LL / 16, BB), 256, 0, stream>>>(x, gate, sy, ssg, scv, shv, out);
    }
}

// Round 9
// 177.936 us; speedup vs baseline: 2.8483x; 2.8483x over previous
//
#include <hip/hip_runtime.h>
#include <math.h>

#define BB   32
#define HHI  56
#define WWI  56
#define CC   256
#define LL   3136      // H*W
#define SS   16
#define NCH  56        // chunks per batch
#define CHL  56        // chunk length
#define NSL  98        // spatial slices for reductions (32 positions each)
#define EPSV 1e-5f

typedef float vfloat4 __attribute__((ext_vector_type(4)));

__device__ __forceinline__ float softplusf(float z) {
    return fmaxf(z, 0.f) + __logf(1.f + __expf(-fabsf(z)));
}
__device__ __forceinline__ float sigmoidf(float z) {
    return 1.f / (1.f + __expf(-z));
}

// -------------------- K1: per-(b,slice) spatial partial sum/max over C ----
// grid (32,98), block 256 (4 waves). LDS combine -> 1 partial per block.
__global__ void k_ca_partial(const float* __restrict__ x,
                             float* __restrict__ psum, float* __restrict__ pmax) {
    const int b = blockIdx.x, sl = blockIdx.y;
    const int wv = threadIdx.x >> 6, l = threadIdx.x & 63;
    const float4* x4 = (const float4*)x;
    const size_t base = ((size_t)b * LL + sl * 32) * 64;
    float4 s  = make_float4(0.f, 0.f, 0.f, 0.f);
    float4 mx = make_float4(-1e30f, -1e30f, -1e30f, -1e30f);
#pragma unroll
    for (int k = 0; k < 8; k++) {
        float4 v = x4[base + (size_t)(k * 4 + wv) * 64 + l];
        s.x += v.x; s.y += v.y; s.z += v.z; s.w += v.w;
        mx.x = fmaxf(mx.x, v.x); mx.y = fmaxf(mx.y, v.y);
        mx.z = fmaxf(mx.z, v.z); mx.w = fmaxf(mx.w, v.w);
    }
    __shared__ float4 ls[4][64], lm[4][64];
    ls[wv][l] = s; lm[wv][l] = mx;
    __syncthreads();
    if (wv == 0) {
#pragma unroll
        for (int w = 1; w < 4; w++) {
            float4 a = ls[w][l], m2 = lm[w][l];
            s.x += a.x; s.y += a.y; s.z += a.z; s.w += a.w;
            mx.x = fmaxf(mx.x, m2.x); mx.y = fmaxf(mx.y, m2.y);
            mx.z = fmaxf(mx.z, m2.z); mx.w = fmaxf(mx.w, m2.w);
        }
        ((float4*)psum)[(b * NSL + sl) * 64 + l] = s;
        ((float4*)pmax)[(b * NSL + sl) * 64 + l] = mx;
    }
}

// -------------------- K2: combine partials + ChannelAttention FC ----------
__global__ void k_ca_fc(const float* __restrict__ psum, const float* __restrict__ pmax,
                        const float* __restrict__ w1, const float* __restrict__ w2,
                        float* __restrict__ gate) {
    const int b = blockIdx.x, tid = threadIdx.x;
    __shared__ float avg[CC], mxs[CC], hsum[16];
    float s = 0.f, mx = -1e30f;
    for (int k = 0; k < NSL; k++) {
        s += psum[(b * NSL + k) * CC + tid];
        mx = fmaxf(mx, pmax[(b * NSL + k) * CC + tid]);
    }
    avg[tid] = s * (1.f / 3136.f);
    mxs[tid] = mx;
    __syncthreads();
    const int r = tid >> 4, l = tid & 15;
    float pa = 0.f, pm = 0.f;
    for (int j = 0; j < 16; j++) {
        float w = w1[r * CC + l * 16 + j];
        pa += avg[l * 16 + j] * w;
        pm += mxs[l * 16 + j] * w;
    }
#pragma unroll
    for (int d = 1; d < 16; d <<= 1) { pa += __shfl_xor(pa, d); pm += __shfl_xor(pm, d); }
    if (l == 0) hsum[r] = fmaxf(pa, 0.f) + fmaxf(pm, 0.f);
    __syncthreads();
    float o = 0.f;
#pragma unroll
    for (int r2 = 0; r2 < 16; r2++) o += hsum[r2] * w2[tid * 16 + r2];
    gate[b * CC + tid] = sigmoidf(o);
}

// -------------------- K3: per-position channel mean/max + delta precompute -
// grid (196, 32): each wave handles 4 positions.
__global__ void k_pos_reduce(const float* __restrict__ x, const float* __restrict__ gate,
                             const float* __restrict__ dw, const float* __restrict__ db,
                             float* __restrict__ m, float* __restrict__ cmax,
                             float4* __restrict__ mdd) {
    const int wv = threadIdx.x >> 6, l = threadIdx.x & 63;
    const int b = blockIdx.y;
    float4 g = ((const float4*)gate)[b * 64 + l];
    const float dwv = dw[0], dbv = db[0];
#pragma unroll
    for (int k = 0; k < 4; k++) {
        const int pos = b * LL + blockIdx.x * 16 + k * 4 + wv;
        float4 v = ((const float4*)x)[(size_t)pos * 64 + l];
        v.x *= g.x; v.y *= g.y; v.z *= g.z; v.w *= g.w;
        float s  = v.x + v.y + v.z + v.w;
        float mm = fmaxf(fmaxf(v.x, v.y), fmaxf(v.z, v.w));
#pragma unroll
        for (int d = 1; d < 64; d <<= 1) {
            s += __shfl_xor(s, d);
            mm = fmaxf(mm, __shfl_xor(mm, d));
        }
        if (l == 0) {
            float mv = s * (1.f / 256.f);
            m[pos] = mv;
            cmax[pos] = mm;
            float dl = softplusf(mv * dwv + dbv);
            mdd[pos] = make_float4(mv, dl, dl * mv, 0.f);
        }
    }
}

// -------------------- K4: fused S6 scan (blocks 0..31) + LSA (blocks 32..63)
__global__ void k_gsa2(const float4* __restrict__ mdd,
                       const float* __restrict__ m, const float* __restrict__ cmax,
                       const float* __restrict__ Bw, const float* __restrict__ Bb,
                       const float* __restrict__ Cw, const float* __restrict__ Cb,
                       const float* __restrict__ A,  const float* __restrict__ wc,
                       float* __restrict__ sy, float* __restrict__ ssg) {
    __shared__ __align__(16) char smem[60928];
    const int tid = threadIdx.x;
    if (blockIdx.x < BB) {
        const int b = blockIdx.x;
        float4* mddl = (float4*)smem;
        float*  Pl   = (float*)(smem + 50176);
        float*  Ql   = (float*)(smem + 50176 + 3584);
        float*  hl   = (float*)(smem + 50176 + 7168);
        for (int i = tid; i < LL; i += 896) mddl[i] = mdd[b * LL + i];
        __syncthreads();
        const int g = tid >> 4, s = tid & 15;
        const float As = A[s], Bws = Bw[s], Bbs = Bb[s];
        const float Cws = Cw[s], Cbs = Cb[s];
        float sumd = 0.f, Q = 0.f;
        for (int t = 0; t < CHL; t++) {
            float4 md = mddl[g * CHL + t];
            float a = __expf(md.y * As);
            Q = a * Q + md.z * (md.x * Bws + Bbs);
            sumd += md.y;
        }
        Pl[g * 16 + s] = __expf(sumd * As);
        Ql[g * 16 + s] = Q;
        __syncthreads();
        if (g == 0) {
            float h = 0.f;
            for (int ch = 0; ch < NCH; ch++) {
                hl[ch * 16 + s] = h;
                h = Pl[ch * 16 + s] * h + Ql[ch * 16 + s];
            }
        }
        __syncthreads();
        float h = hl[g * 16 + s];
        for (int t = 0; t < CHL; t++) {
            float4 md = mddl[g * CHL + t];
            float a = __expf(md.y * As);
            h = a * h + md.z * (md.x * Bws + Bbs);
            float p = h * (md.x * Cws + Cbs);
#pragma unroll
            for (int d = 1; d < 16; d <<= 1) p += __shfl_xor(p, d);
            if (s == 0) sy[b * LL + g * CHL + t] = sigmoidf(p);
        }
    } else {
        const int b = blockIdx.x - BB;
        float* ml = (float*)smem;
        float* cl = (float*)(smem + 12544);
        float* wl = (float*)(smem + 25088);
        for (int i = tid; i < LL; i += 896) {
            ml[i] = m[b * LL + i];
            cl[i] = cmax[b * LL + i];
        }
        if (tid < 98) wl[tid] = wc[tid];
        __syncthreads();
        for (int pos = tid; pos < LL; pos += 896) {
            const int h0 = pos / WWI, w0 = pos - h0 * WWI;
            float acc = 0.f;
#pragma unroll
            for (int kh = 0; kh < 7; kh++) {
                int hh = h0 + kh - 3;
                if ((unsigned)hh >= (unsigned)HHI) continue;
                const int rb = hh * WWI;
#pragma unroll
                for (int kw = 0; kw < 7; kw++) {
                    int ww = w0 + kw - 3;
                    if ((unsigned)ww >= (unsigned)WWI) continue;
                    acc += ml[rb + ww] * wl[(kh * 7 + kw) * 2]
                         + cl[rb + ww] * wl[(kh * 7 + kw) * 2 + 1];
                }
            }
            ssg[b * LL + pos] = sigmoidf(acc);
        }
    }
}

// -------------------- K5: BN partial stats per (b,slice) ------------------
__global__ void k_bnstat(const float* __restrict__ x, const float* __restrict__ gate,
                         const float* __restrict__ sy, const float* __restrict__ ssg,
                         float* __restrict__ pb) {
    const int b = blockIdx.x, sl = blockIdx.y;
    const int wv = threadIdx.x >> 6, l = threadIdx.x & 63;
    const float4* x4 = (const float4*)x;
    float4 g = ((const float4*)gate)[b * 64 + l];
    float4 s = make_float4(0.f, 0.f, 0.f, 0.f);
    float4 q = make_float4(0.f, 0.f, 0.f, 0.f);
#pragma unroll
    for (int k = 0; k < 8; k++) {
        int pos = b * LL + sl * 32 + k * 4 + wv;
        float4 v = x4[(size_t)pos * 64 + l];
        float g2 = sy[pos] + ssg[pos];
        float fx = v.x * g.x * g2, fy = v.y * g.y * g2, fz = v.z * g.z * g2, fw = v.w * g.w * g2;
        s.x += fx; s.y += fy; s.z += fz; s.w += fw;
        q.x += fx * fx; q.y += fy * fy; q.z += fz * fz; q.w += fw * fw;
    }
    __shared__ float4 ls[4][64], lq[4][64];
    ls[wv][l] = s; lq[wv][l] = q;
    __syncthreads();
    if (wv == 0) {
#pragma unroll
        for (int w = 1; w < 4; w++) {
            float4 a = ls[w][l], c = lq[w][l];
            s.x += a.x; s.y += a.y; s.z += a.z; s.w += a.w;
            q.x += c.x; q.y += c.y; q.z += c.z; q.w += c.w;
        }
        ((float4*)pb)[(b * NSL + sl) * 128 + l] = s;
        ((float4*)pb)[(b * NSL + sl) * 128 + 64 + l] = q;
    }
}

// -------------------- K6: BN reduce + finalize (coalesced) ----------------
// grid 16, block 512. Block g: channels g*16..g*16+15.
__global__ void k_bnfin(const float* __restrict__ pb,
                        const float* __restrict__ gamma, const float* __restrict__ beta,
                        float* __restrict__ sc, float* __restrict__ sh) {
    const int g = blockIdx.x;
    const int tid = threadIdx.x;
    const int half = tid >> 8;            // 0 = sum, 1 = sumsq
    const int t = tid & 255;
    const int cl = t & 15, r = t >> 4;    // r = 0..15
    const int col = half * 256 + g * 16 + cl;
    float acc = 0.f;
    for (int k = r; k < BB * NSL; k += 16) {
        acc += pb[(size_t)k * 512 + col];
    }
    __shared__ float red[2][16][16];      // [half][r][cl]
    red[half][r][cl] = acc;
    __syncthreads();
    if (tid < 32) {
        const int h2 = tid >> 4, c2 = tid & 15;
        float s0 = 0.f;
#pragma unroll
        for (int rr = 0; rr < 16; rr++) s0 += red[h2][rr][c2];
        red[h2][0][c2] = s0;
    }
    __syncthreads();
    if (tid < 16) {
        const int c = g * 16 + tid;
        const float inv = 1.f / (float)(BB * LL);
        float mean = red[0][0][tid] * inv;
        float var  = red[1][0][tid] * inv - mean * mean;
        float sv = gamma[c] * rsqrtf(var + EPSV);
        sc[c] = sv;
        sh[c] = beta[c] - mean * sv;
    }
}

// -------------------- K7: normalize + ReLU + nontemporal write ------------
// grid (196, 32): each wave handles 4 positions.
__global__ void k_final(const float* __restrict__ x, const float* __restrict__ gate,
                        const float* __restrict__ sy, const float* __restrict__ ssg,
                        const float* __restrict__ sc, const float* __restrict__ sh,
                        float* __restrict__ out) {
    const int wv = threadIdx.x >> 6, l = threadIdx.x & 63;
    const int b = blockIdx.y;
    const float4 scv = ((const float4*)sc)[l];
    const float4 shv = ((const float4*)sh)[l];
    const float4 g = ((const float4*)gate)[b * 64 + l];
#pragma unroll
    for (int k = 0; k < 4; k++) {
        const int pos = b * LL + blockIdx.x * 16 + k * 4 + wv;
        float4 v = ((const float4*)x)[(size_t)pos * 64 + l];
        float g2 = sy[pos] + ssg[pos];
        vfloat4 o;
        o.x = fmaxf(v.x * g.x * g2 * scv.x + shv.x, 0.f);
        o.y = fmaxf(v.y * g.y * g2 * scv.y + shv.y, 0.f);
        o.z = fmaxf(v.z * g.z * g2 * scv.z + shv.z, 0.f);
        o.w = fmaxf(v.w * g.w * g2 * scv.w + shv.w, 0.f);
        __builtin_nontemporal_store(o, (vfloat4*)out + (size_t)pos * 64 + l);
    }
}

extern "C" void kernel_launch(void* const* d_in, const int* in_sizes, int n_in,
                              void* d_out, int out_size, void* d_ws, size_t ws_size,
                              hipStream_t stream) {
    const float* x     = (const float*)d_in[0];
    const float* ca_w1 = (const float*)d_in[1];
    const float* ca_w2 = (const float*)d_in[2];
    const float* lsa_w = (const float*)d_in[3];
    const float* A     = (const float*)d_in[4];
    const float* d_wp  = (const float*)d_in[5];
    const float* d_bp  = (const float*)d_in[6];
    const float* B_wp  = (const float*)d_in[7];
    const float* B_bp  = (const float*)d_in[8];
    const float* C_wp  = (const float*)d_in[9];
    const float* C_bp  = (const float*)d_in[10];
    const float* bn_g  = (const float*)d_in[11];
    const float* bn_b  = (const float*)d_in[12];
    float* out = (float*)d_out;

    // Large partial buffers live in d_out (fully overwritten by k_final).
    float* psum = out;                         // 32*98*256
    float* pmax = psum + BB * NSL * CC;        // 32*98*256
    float* pb   = pmax + BB * NSL * CC;        // 32*98*512  (total 3.2M floats < 25.7M)

    float* ws    = (float*)d_ws;
    float4* mdd  = (float4*)ws;                // 100352 float4 (16B aligned at base)
    float* gate  = ws + 401408;                // 8192
    float* m     = gate + 8192;                // 100352
    float* cmax  = m + 100352;                 // 100352
    float* sy    = cmax + 100352;              // 100352
    float* ssg   = sy + 100352;                // 100352
    float* scv   = ssg + 100352;               // 256
    float* shv   = scv + 256;                  // 256

    k_ca_partial<<<dim3(BB, NSL), 256, 0, stream>>>(x, psum, pmax);
    k_ca_fc<<<BB, 256, 0, stream>>>(psum, pmax, ca_w1, ca_w2, gate);
    k_pos_reduce<<<dim3(LL / 16, BB), 256, 0, stream>>>(x, gate, d_wp, d_bp, m, cmax, mdd);
    k_gsa2<<<2 * BB, 896, 0, stream>>>(mdd, m, cmax, B_wp, B_bp, C_wp, C_bp, A, lsa_w, sy, ssg);
    k_bnstat<<<dim3(BB, NSL), 256, 0, stream>>>(x, gate, sy, ssg, pb);
    k_bnfin<<<16, 512, 0, stream>>>(pb, bn_g, bn_b, scv, shv);
    k_final<<<dim3(LL / 16, BB), 256, 0, stream>>>(x, gate, sy, ssg, scv, shv, out);
}

// Round 10
// 123.055 us; speedup vs baseline: 4.1187x; 1.4460x over previous
//
#include <hip/hip_runtime.h>
#include <math.h>

#define BB   32
#define HHI  56
#define WWI  56
#define CC   256
#define LL   3136      // H*W
#define SS   16
#define NCH  56        // chunks per batch
#define CHL  56        // chunk length
#define NSL  98        // spatial slices for reductions (32 positions each)
#define EPSV 1e-5f

typedef float vfloat4 __attribute__((ext_vector_type(4)));

__device__ __forceinline__ float softplusf(float z) {
    return fmaxf(z, 0.f) + __logf(1.f + __expf(-fabsf(z)));
}
__device__ __forceinline__ float sigmoidf(float z) {
    return 1.f / (1.f + __expf(-z));
}

// -------------------- K1: per-(b,slice) spatial partial sum/max over C ----
// grid (32,98), block 256 (4 waves). LDS combine -> 1 partial per block.
__global__ void k_ca_partial(const float* __restrict__ x,
                             float* __restrict__ psum, float* __restrict__ pmax) {
    const int b = blockIdx.x, sl = blockIdx.y;
    const int wv = threadIdx.x >> 6, l = threadIdx.x & 63;
    const float4* x4 = (const float4*)x;
    const size_t base = ((size_t)b * LL + sl * 32) * 64;
    float4 s  = make_float4(0.f, 0.f, 0.f, 0.f);
    float4 mx = make_float4(-1e30f, -1e30f, -1e30f, -1e30f);
#pragma unroll
    for (int k = 0; k < 8; k++) {
        float4 v = x4[base + (size_t)(k * 4 + wv) * 64 + l];
        s.x += v.x; s.y += v.y; s.z += v.z; s.w += v.w;
        mx.x = fmaxf(mx.x, v.x); mx.y = fmaxf(mx.y, v.y);
        mx.z = fmaxf(mx.z, v.z); mx.w = fmaxf(mx.w, v.w);
    }
    __shared__ float4 ls[4][64], lm[4][64];
    ls[wv][l] = s; lm[wv][l] = mx;
    __syncthreads();
    if (wv == 0) {
#pragma unroll
        for (int w = 1; w < 4; w++) {
            float4 a = ls[w][l], m2 = lm[w][l];
            s.x += a.x; s.y += a.y; s.z += a.z; s.w += a.w;
            mx.x = fmaxf(mx.x, m2.x); mx.y = fmaxf(mx.y, m2.y);
            mx.z = fmaxf(mx.z, m2.z); mx.w = fmaxf(mx.w, m2.w);
        }
        ((float4*)psum)[(b * NSL + sl) * 64 + l] = s;
        ((float4*)pmax)[(b * NSL + sl) * 64 + l] = mx;
    }
}

// -------------------- K2: combine partials + ChannelAttention FC ----------
__global__ void k_ca_fc(const float* __restrict__ psum, const float* __restrict__ pmax,
                        const float* __restrict__ w1, const float* __restrict__ w2,
                        float* __restrict__ gate) {
    const int b = blockIdx.x, tid = threadIdx.x;
    __shared__ float avg[CC], mxs[CC], hsum[16];
    float s = 0.f, mx = -1e30f;
    for (int k = 0; k < NSL; k++) {
        s += psum[(b * NSL + k) * CC + tid];
        mx = fmaxf(mx, pmax[(b * NSL + k) * CC + tid]);
    }
    avg[tid] = s * (1.f / 3136.f);
    mxs[tid] = mx;
    __syncthreads();
    const int r = tid >> 4, l = tid & 15;
    float pa = 0.f, pm = 0.f;
    for (int j = 0; j < 16; j++) {
        float w = w1[r * CC + l * 16 + j];
        pa += avg[l * 16 + j] * w;
        pm += mxs[l * 16 + j] * w;
    }
#pragma unroll
    for (int d = 1; d < 16; d <<= 1) { pa += __shfl_xor(pa, d); pm += __shfl_xor(pm, d); }
    if (l == 0) hsum[r] = fmaxf(pa, 0.f) + fmaxf(pm, 0.f);
    __syncthreads();
    float o = 0.f;
#pragma unroll
    for (int r2 = 0; r2 < 16; r2++) o += hsum[r2] * w2[tid * 16 + r2];
    gate[b * CC + tid] = sigmoidf(o);
}

// -------------------- K3: per-position channel mean/max + delta precompute -
// grid (196, 32): each wave handles 4 positions.
__global__ void k_pos_reduce(const float* __restrict__ x, const float* __restrict__ gate,
                             const float* __restrict__ dw, const float* __restrict__ db,
                             float* __restrict__ m, float* __restrict__ cmax,
                             float4* __restrict__ mdd) {
    const int wv = threadIdx.x >> 6, l = threadIdx.x & 63;
    const int b = blockIdx.y;
    float4 g = ((const float4*)gate)[b * 64 + l];
    const float dwv = dw[0], dbv = db[0];
#pragma unroll
    for (int k = 0; k < 4; k++) {
        const int pos = b * LL + blockIdx.x * 16 + k * 4 + wv;
        float4 v = ((const float4*)x)[(size_t)pos * 64 + l];
        v.x *= g.x; v.y *= g.y; v.z *= g.z; v.w *= g.w;
        float s  = v.x + v.y + v.z + v.w;
        float mm = fmaxf(fmaxf(v.x, v.y), fmaxf(v.z, v.w));
#pragma unroll
        for (int d = 1; d < 64; d <<= 1) {
            s += __shfl_xor(s, d);
            mm = fmaxf(mm, __shfl_xor(mm, d));
        }
        if (l == 0) {
            float mv = s * (1.f / 256.f);
            m[pos] = mv;
            cmax[pos] = mm;
            float dl = softplusf(mv * dwv + dbv);
            mdd[pos] = make_float4(mv, dl, dl * mv, 0.f);
        }
    }
}

// -------------------- K4: fused S6 scan (blocks 0..31) + LSA (blocks 32..63)
__global__ void k_gsa2(const float4* __restrict__ mdd,
                       const float* __restrict__ m, const float* __restrict__ cmax,
                       const float* __restrict__ Bw, const float* __restrict__ Bb,
                       const float* __restrict__ Cw, const float* __restrict__ Cb,
                       const float* __restrict__ A,  const float* __restrict__ wc,
                       float* __restrict__ sy, float* __restrict__ ssg) {
    __shared__ __align__(16) char smem[60928];
    const int tid = threadIdx.x;
    if (blockIdx.x < BB) {
        const int b = blockIdx.x;
        float4* mddl = (float4*)smem;
        float*  Pl   = (float*)(smem + 50176);
        float*  Ql   = (float*)(smem + 50176 + 3584);
        float*  hl   = (float*)(smem + 50176 + 7168);
        for (int i = tid; i < LL; i += 896) mddl[i] = mdd[b * LL + i];
        __syncthreads();
        const int g = tid >> 4, s = tid & 15;
        const float As = A[s], Bws = Bw[s], Bbs = Bb[s];
        const float Cws = Cw[s], Cbs = Cb[s];
        float sumd = 0.f, Q = 0.f;
        for (int t = 0; t < CHL; t++) {
            float4 md = mddl[g * CHL + t];
            float a = __expf(md.y * As);
            Q = a * Q + md.z * (md.x * Bws + Bbs);
            sumd += md.y;
        }
        Pl[g * 16 + s] = __expf(sumd * As);
        Ql[g * 16 + s] = Q;
        __syncthreads();
        if (g == 0) {
            float h = 0.f;
            for (int ch = 0; ch < NCH; ch++) {
                hl[ch * 16 + s] = h;
                h = Pl[ch * 16 + s] * h + Ql[ch * 16 + s];
            }
        }
        __syncthreads();
        float h = hl[g * 16 + s];
        for (int t = 0; t < CHL; t++) {
            float4 md = mddl[g * CHL + t];
            float a = __expf(md.y * As);
            h = a * h + md.z * (md.x * Bws + Bbs);
            float p = h * (md.x * Cws + Cbs);
#pragma unroll
            for (int d = 1; d < 16; d <<= 1) p += __shfl_xor(p, d);
            if (s == 0) sy[b * LL + g * CHL + t] = sigmoidf(p);
        }
    } else {
        const int b = blockIdx.x - BB;
        float* ml = (float*)smem;
        float* cl = (float*)(smem + 12544);
        float* wl = (float*)(smem + 25088);
        for (int i = tid; i < LL; i += 896) {
            ml[i] = m[b * LL + i];
            cl[i] = cmax[b * LL + i];
        }
        if (tid < 98) wl[tid] = wc[tid];
        __syncthreads();
        for (int pos = tid; pos < LL; pos += 896) {
            const int h0 = pos / WWI, w0 = pos - h0 * WWI;
            float acc = 0.f;
#pragma unroll
            for (int kh = 0; kh < 7; kh++) {
                int hh = h0 + kh - 3;
                if ((unsigned)hh >= (unsigned)HHI) continue;
                const int rb = hh * WWI;
#pragma unroll
                for (int kw = 0; kw < 7; kw++) {
                    int ww = w0 + kw - 3;
                    if ((unsigned)ww >= (unsigned)WWI) continue;
                    acc += ml[rb + ww] * wl[(kh * 7 + kw) * 2]
                         + cl[rb + ww] * wl[(kh * 7 + kw) * 2 + 1];
                }
            }
            ssg[b * LL + pos] = sigmoidf(acc);
        }
    }
}

// -------------------- K5: BN partial stats per (b,slice) ------------------
__global__ void k_bnstat(const float* __restrict__ x, const float* __restrict__ gate,
                         const float* __restrict__ sy, const float* __restrict__ ssg,
                         float* __restrict__ pb) {
    const int b = blockIdx.x, sl = blockIdx.y;
    const int wv = threadIdx.x >> 6, l = threadIdx.x & 63;
    const float4* x4 = (const float4*)x;
    float4 g = ((const float4*)gate)[b * 64 + l];
    float4 s = make_float4(0.f, 0.f, 0.f, 0.f);
    float4 q = make_float4(0.f, 0.f, 0.f, 0.f);
#pragma unroll
    for (int k = 0; k < 8; k++) {
        int pos = b * LL + sl * 32 + k * 4 + wv;
        float4 v = x4[(size_t)pos * 64 + l];
        float g2 = sy[pos] + ssg[pos];
        float fx = v.x * g.x * g2, fy = v.y * g.y * g2, fz = v.z * g.z * g2, fw = v.w * g.w * g2;
        s.x += fx; s.y += fy; s.z += fz; s.w += fw;
        q.x += fx * fx; q.y += fy * fy; q.z += fz * fz; q.w += fw * fw;
    }
    __shared__ float4 ls[4][64], lq[4][64];
    ls[wv][l] = s; lq[wv][l] = q;
    __syncthreads();
    if (wv == 0) {
#pragma unroll
        for (int w = 1; w < 4; w++) {
            float4 a = ls[w][l], c = lq[w][l];
            s.x += a.x; s.y += a.y; s.z += a.z; s.w += a.w;
            q.x += c.x; q.y += c.y; q.z += c.z; q.w += c.w;
        }
        ((float4*)pb)[(b * NSL + sl) * 128 + l] = s;
        ((float4*)pb)[(b * NSL + sl) * 128 + 64 + l] = q;
    }
}

// -------------------- K6a: BN reduce stage 1 (coalesced, unrolled) --------
// grid 64, block 512. Block i sums rows [i*49, i*49+49) of pb[3136][512].
__global__ void k_bnred(const float* __restrict__ pb, float* __restrict__ partial) {
    const int i = blockIdx.x, tid = threadIdx.x;
    const float* p = pb + (size_t)i * 49 * 512 + tid;
    float acc = 0.f;
#pragma unroll
    for (int r = 0; r < 49; r++) acc += p[(size_t)r * 512];
    partial[i * 512 + tid] = acc;
}

// -------------------- K6b: BN final reduce + scale/shift ------------------
// 1 block, 512 threads. partial[64][512] -> scv/shv[256].
__global__ void k_bnfin(const float* __restrict__ partial,
                        const float* __restrict__ gamma, const float* __restrict__ beta,
                        float* __restrict__ sc, float* __restrict__ sh) {
    const int tid = threadIdx.x;
    float acc = 0.f;
#pragma unroll
    for (int i = 0; i < 64; i++) acc += partial[i * 512 + tid];
    __shared__ float red[512];
    red[tid] = acc;
    __syncthreads();
    if (tid < 256) {
        const float inv = 1.f / (float)(BB * LL);
        float mean = red[tid] * inv;
        float var  = red[256 + tid] * inv - mean * mean;
        float sv = gamma[tid] * rsqrtf(var + EPSV);
        sc[tid] = sv;
        sh[tid] = beta[tid] - mean * sv;
    }
}

// -------------------- K7: normalize + ReLU + nontemporal write ------------
// grid (196, 32): each wave handles 4 positions.
__global__ void k_final(const float* __restrict__ x, const float* __restrict__ gate,
                        const float* __restrict__ sy, const float* __restrict__ ssg,
                        const float* __restrict__ sc, const float* __restrict__ sh,
                        float* __restrict__ out) {
    const int wv = threadIdx.x >> 6, l = threadIdx.x & 63;
    const int b = blockIdx.y;
    const float4 scv = ((const float4*)sc)[l];
    const float4 shv = ((const float4*)sh)[l];
    const float4 g = ((const float4*)gate)[b * 64 + l];
#pragma unroll
    for (int k = 0; k < 4; k++) {
        const int pos = b * LL + blockIdx.x * 16 + k * 4 + wv;
        float4 v = ((const float4*)x)[(size_t)pos * 64 + l];
        float g2 = sy[pos] + ssg[pos];
        vfloat4 o;
        o.x = fmaxf(v.x * g.x * g2 * scv.x + shv.x, 0.f);
        o.y = fmaxf(v.y * g.y * g2 * scv.y + shv.y, 0.f);
        o.z = fmaxf(v.z * g.z * g2 * scv.z + shv.z, 0.f);
        o.w = fmaxf(v.w * g.w * g2 * scv.w + shv.w, 0.f);
        __builtin_nontemporal_store(o, (vfloat4*)out + (size_t)pos * 64 + l);
    }
}

extern "C" void kernel_launch(void* const* d_in, const int* in_sizes, int n_in,
                              void* d_out, int out_size, void* d_ws, size_t ws_size,
                              hipStream_t stream) {
    const float* x     = (const float*)d_in[0];
    const float* ca_w1 = (const float*)d_in[1];
    const float* ca_w2 = (const float*)d_in[2];
    const float* lsa_w = (const float*)d_in[3];
    const float* A     = (const float*)d_in[4];
    const float* d_wp  = (const float*)d_in[5];
    const float* d_bp  = (const float*)d_in[6];
    const float* B_wp  = (const float*)d_in[7];
    const float* B_bp  = (const float*)d_in[8];
    const float* C_wp  = (const float*)d_in[9];
    const float* C_bp  = (const float*)d_in[10];
    const float* bn_g  = (const float*)d_in[11];
    const float* bn_b  = (const float*)d_in[12];
    float* out = (float*)d_out;

    // Large partial buffers live in d_out (fully overwritten by k_final).
    float* psum = out;                         // 32*98*256
    float* pmax = psum + BB * NSL * CC;        // 32*98*256
    float* pb   = pmax + BB * NSL * CC;        // 32*98*512  (total 3.2M floats < 25.7M)

    float* ws      = (float*)d_ws;
    float4* mdd    = (float4*)ws;              // 100352 float4 (16B aligned at base)
    float* gate    = ws + 401408;              // 8192
    float* m       = gate + 8192;              // 100352
    float* cmax    = m + 100352;               // 100352
    float* sy      = cmax + 100352;            // 100352
    float* ssg     = sy + 100352;              // 100352
    float* scv     = ssg + 100352;             // 256
    float* shv     = scv + 256;                // 256
    float* partial = shv + 256;                // 64*512 = 32768

    k_ca_partial<<<dim3(BB, NSL), 256, 0, stream>>>(x, psum, pmax);
    k_ca_fc<<<BB, 256, 0, stream>>>(psum, pmax, ca_w1, ca_w2, gate);
    k_pos_reduce<<<dim3(LL / 16, BB), 256, 0, stream>>>(x, gate, d_wp, d_bp, m, cmax, mdd);
    k_gsa2<<<2 * BB, 896, 0, stream>>>(mdd, m, cmax, B_wp, B_bp, C_wp, C_bp, A, lsa_w, sy, ssg);
    k_bnstat<<<dim3(BB, NSL), 256, 0, stream>>>(x, gate, sy, ssg, pb);
    k_bnred<<<64, 512, 0, stream>>>(pb, partial);
    k_bnfin<<<1, 512, 0, stream>>>(partial, bn_g, bn_b, scv, shv);
    k_final<<<dim3(LL / 16, BB), 256, 0, stream>>>(x, gate, sy, ssg, scv, shv, out);
}